// Round 2
// baseline (8354.189 us; speedup 1.0000x reference)
//
#include <hip/hip_runtime.h>
#include <hip/hip_bf16.h>
#include <cstdio>

#define INV2 0.70710678118654752440f
typedef __hip_bfloat16 bf16;

__device__ __forceinline__ float silu_f(float v) { return v / (1.0f + __expf(-v)); }

__device__ __forceinline__ float bf2f(unsigned short u) {
    union { unsigned int i; float f; } t; t.i = ((unsigned int)u) << 16; return t.f;
}
__device__ __forceinline__ float toF(float v) { return v; }
__device__ __forceinline__ float toF(bf16 v) { return __bfloat162float(v); }
__device__ __forceinline__ void stF(float* p, float v) { *p = v; }
__device__ __forceinline__ void stF(bf16* p, float v) { *p = __float2bfloat16(v); }
__device__ __forceinline__ float4 ld4(const float* p) { return *(const float4*)p; }
__device__ __forceinline__ float4 ld4(const bf16* p) {
    const ushort4 u = *(const ushort4*)p;
    return make_float4(bf2f(u.x), bf2f(u.y), bf2f(u.z), bf2f(u.w));
}

enum { AM_NORMAL = 0, AM_MUL2 = 1, AM_GATHER = 2, AM_SILU = 3 };
enum { EP_PLAIN = 0, EP_SILU = 1, EP_ACCUM = 2, EP_RES2 = 3, EP_RESADD = 4, EP_HEADRES = 5 };

// C[M,N] = epilogue( amode(A)[M,K] @ B[K,N] ), B always f32 row-major with ldb
template <int AMODE, int EPI, typename AT, typename CT>
__global__ __launch_bounds__(256) void gemm_k(
    const AT* __restrict__ A, const AT* __restrict__ A2,
    const int* __restrict__ gs, const int* __restrict__ gt,
    const float* __restrict__ B, int ldb,
    CT* __restrict__ C, const CT* __restrict__ X,
    int Mrows, int Ncols, int K)
{
    __shared__ float As[16][64];
    __shared__ float Bs[16][64];
    const int tid = threadIdx.x;
    const int row0 = blockIdx.x * 64, col0 = blockIdx.y * 64;
    const int tx = tid & 15, ty = tid >> 4;
    const int ar = tid >> 2, ak4 = (tid & 3) * 4;   // A tile: row ar, k ak4..+3
    const int bc = tid & 63, bk4 = (tid >> 6) * 4;  // B tile: col bc, k bk4..+3
    const int grow = row0 + ar;
    const bool rowok = (grow < Mrows);

    int is_ = 0, it_ = 0;
    if (AMODE == AM_GATHER && rowok) { is_ = gs[grow]; it_ = gt[grow]; }

    float acc[4][4] = {};

    for (int k0 = 0; k0 < K; k0 += 16) {
        float4 av = make_float4(0.f, 0.f, 0.f, 0.f);
        if (rowok) {
            const int k = k0 + ak4;
            if (AMODE == AM_NORMAL) {
                av = ld4(A + (size_t)grow * K + k);
            } else if (AMODE == AM_SILU) {
                av = ld4(A + (size_t)grow * K + k);
                av.x = silu_f(av.x); av.y = silu_f(av.y);
                av.z = silu_f(av.z); av.w = silu_f(av.w);
            } else if (AMODE == AM_MUL2) {
                const float4 p = ld4(A + (size_t)grow * K + k);
                const float4 q = ld4(A2 + (size_t)grow * K + k);
                av = make_float4(p.x * q.x, p.y * q.y, p.z * q.z, p.w * q.w);
            } else {  // AM_GATHER: K==384, regions of 128 (h[is] | h[it] | rbf)
                const AT* src;
                if (k < 128)      src = A + (size_t)is_ * 128 + k;
                else if (k < 256) src = A + (size_t)it_ * 128 + (k - 128);
                else              src = A2 + (size_t)grow * 128 + (k - 256);
                av = ld4(src);
            }
        }
        As[ak4 + 0][ar] = av.x; As[ak4 + 1][ar] = av.y;
        As[ak4 + 2][ar] = av.z; As[ak4 + 3][ar] = av.w;
        {
            const float* bp = B + (size_t)(k0 + bk4) * ldb + col0 + bc;
            Bs[bk4 + 0][bc] = bp[0];
            Bs[bk4 + 1][bc] = bp[ldb];
            Bs[bk4 + 2][bc] = bp[2 * (size_t)ldb];
            Bs[bk4 + 3][bc] = bp[3 * (size_t)ldb];
        }
        __syncthreads();
#pragma unroll
        for (int kk = 0; kk < 16; ++kk) {
            float a[4], b[4];
#pragma unroll
            for (int i = 0; i < 4; i++) a[i] = As[kk][ty * 4 + i];
#pragma unroll
            for (int j = 0; j < 4; j++) b[j] = Bs[kk][tx * 4 + j];
#pragma unroll
            for (int i = 0; i < 4; i++)
#pragma unroll
                for (int j = 0; j < 4; j++) acc[i][j] += a[i] * b[j];
        }
        __syncthreads();
    }

#pragma unroll
    for (int i = 0; i < 4; i++) {
        const int r = row0 + ty * 4 + i;
        if (r >= Mrows) continue;
#pragma unroll
        for (int j = 0; j < 4; j++) {
            const int c = col0 + tx * 4 + j;
            const size_t o = (size_t)r * Ncols + c;
            const float v = acc[i][j];
            if (EPI == EP_PLAIN)        stF(&C[o], v);
            else if (EPI == EP_SILU)    stF(&C[o], silu_f(v));
            else if (EPI == EP_ACCUM)   stF(&C[o], toF(C[o]) + v);
            else if (EPI == EP_RES2)    stF(&C[o], (toF(C[o]) + silu_f(v)) * INV2);
            else if (EPI == EP_RESADD)  stF(&C[o], toF(C[o]) + (toF(X[o]) + silu_f(v)) * INV2);
            else if (EPI == EP_HEADRES) stF(&C[o], (silu_f(toF(X[o])) + silu_f(v)) * INV2);
        }
    }
}

__global__ __launch_bounds__(256) void embed_h(const int* __restrict__ z,
                                               const float* __restrict__ tab,
                                               float* __restrict__ h, int N)
{
    const int gid = blockIdx.x * 256 + threadIdx.x;
    const int n = gid >> 7, j = gid & 127;
    if (n >= N) return;
    h[(size_t)n * 128 + j] = tab[(size_t)z[n] * 128 + j];
}

// Wt[i, c*64+o] = Wb[c, i, o]   (Wb: [16,64,64])
__global__ __launch_bounds__(256) void transpose_wbil(const float* __restrict__ Wb,
                                                      float* __restrict__ Wt)
{
    const int idx = blockIdx.x * 256 + threadIdx.x;  // 65536
    const int o = idx & 63, i = (idx >> 6) & 63, c = idx >> 12;
    Wt[(size_t)i * 1024 + c * 64 + o] = Wb[idx];
}

// agg[ca[t],o] += sum_{cc<4} (cbf[t,:7].Wcb[:,cc0+cc]) * Wxc[ba[t], cc*64+o]
__global__ __launch_bounds__(256) void triplet_combine(
    const bf16* __restrict__ Wxc,   // [E,256]
    const float* __restrict__ cbf,  // [T,7]
    const float* __restrict__ Wcb,  // [7,16] (this block's)
    const int* __restrict__ ba, const int* __restrict__ ca,
    float* __restrict__ agg, int T, int cc0)
{
    const int gid = blockIdx.x * 256 + threadIdx.x;
    const int t = gid >> 6, o = gid & 63;
    if (t >= T) return;
    const int e = ba[t], eo = ca[t];
    const float* cr = cbf + (size_t)t * 7;
    float c0 = cr[0], c1 = cr[1], c2 = cr[2], c3 = cr[3], c4 = cr[4], c5 = cr[5], c6 = cr[6];
    const bf16* w = Wxc + (size_t)e * 256 + o;
    float y = 0.f;
#pragma unroll
    for (int cc = 0; cc < 4; cc++) {
        const float* wc = Wcb + cc0 + cc;
        const float cb = c0 * wc[0] + c1 * wc[16] + c2 * wc[32] + c3 * wc[48] +
                         c4 * wc[64] + c5 * wc[80] + c6 * wc[96];
        y += cb * toF(w[cc * 64]);
    }
    atomicAdd(&agg[(size_t)eo * 64 + o], y);
}

__global__ __launch_bounds__(256) void scatter_ha(const bf16* __restrict__ xa,
                                                  const int* __restrict__ idxt,
                                                  float* __restrict__ ha, int E)
{
    const int gid = blockIdx.x * 256 + threadIdx.x;
    const int e = gid >> 7, j = gid & 127;
    if (e >= E) return;
    atomicAdd(&ha[(size_t)idxt[e] * 128 + j], toF(xa[(size_t)e * 128 + j]));
}

// one wave per row: out[row*ostride] = X[row,:width] . w
template <typename AT>
__global__ __launch_bounds__(256) void rowdot(const AT* __restrict__ Xm,
                                              const float* __restrict__ w,
                                              float* __restrict__ outv,
                                              int rows, int width, int ostride)
{
    const int wid = (blockIdx.x * 256 + threadIdx.x) >> 6;
    const int lane = threadIdx.x & 63;
    if (wid >= rows) return;
    float s = 0.f;
    for (int q = lane; q < width; q += 64) s += toF(Xm[(size_t)wid * width + q]) * w[q];
#pragma unroll
    for (int off = 32; off > 0; off >>= 1) s += __shfl_down(s, off);
    if (lane == 0) outv[(size_t)wid * ostride] = s;
}

__global__ __launch_bounds__(256) void scatter_forces(const float* __restrict__ Fe,
                                                      const float* __restrict__ Vst,
                                                      const int* __restrict__ idxt,
                                                      float* __restrict__ out, int E)
{
    const int e = blockIdx.x * 256 + threadIdx.x;
    if (e >= E) return;
    const float f = Fe[e];
    const int n = idxt[e];
    atomicAdd(&out[(size_t)n * 4 + 1], f * Vst[(size_t)e * 3 + 0]);
    atomicAdd(&out[(size_t)n * 4 + 2], f * Vst[(size_t)e * 3 + 1]);
    atomicAdd(&out[(size_t)n * 4 + 3], f * Vst[(size_t)e * 3 + 2]);
}

#define GEMM(AM, EP, Aptr, A2ptr, GS, GT, Bptr, LDB, Cptr, Xptr, MR, NC, KK)              \
    gemm_k<AM, EP><<<dim3(((MR) + 63) / 64, (NC) / 64), 256, 0, stream>>>(                \
        Aptr, A2ptr, GS, GT, Bptr, LDB, Cptr, Xptr, MR, NC, KK)

extern "C" void kernel_launch(void* const* d_in, const int* in_sizes, int n_in,
                              void* d_out, int out_size, void* d_ws, size_t ws_size,
                              hipStream_t stream)
{
    const int N = in_sizes[0];
    const int E = in_sizes[1];
    const int T = in_sizes[3];
    const int NB = 2;

    const int*   z        = (const int*)d_in[0];
    const int*   idx_s    = (const int*)d_in[1];
    const int*   idx_t    = (const int*)d_in[2];
    const int*   id3_ba   = (const int*)d_in[3];
    const int*   id3_ca   = (const int*)d_in[4];
    const float* rbf      = (const float*)d_in[5];
    const float* cbf      = (const float*)d_in[6];
    const float* V_st     = (const float*)d_in[7];
    const float* atom_tab = (const float*)d_in[8];
    const float* W_edge_in= (const float*)d_in[9];
    const float* rbf_w3   = (const float*)d_in[10];
    const float* W_down   = (const float*)d_in[11];
    const float* W_cbf    = (const float*)d_in[12];
    const float* W_bil    = (const float*)d_in[13];
    const float* W_up     = (const float*)d_in[14];
    const float* W_res_e  = (const float*)d_in[15];
    const float* rbf_wh   = (const float*)d_in[16];
    const float* W_e2a    = (const float*)d_in[17];
    const float* W_res_a  = (const float*)d_in[18];
    const float* W_outE_in  = (const float*)d_in[19];
    const float* W_outE_res = (const float*)d_in[20];
    const float* W_outE_fin = (const float*)d_in[21];
    const float* W_outF_in  = (const float*)d_in[22];
    const float* W_outF_res = (const float*)d_in[23];
    const float* W_outF_fin = (const float*)d_in[24];

    float* out = (float*)d_out;

    // ---- workspace layout (bytes) ----
    char* base = (char*)d_ws;
    size_t off = 0;
    auto alloc = [&](size_t nbytes) { char* p = base + off; off += (nbytes + 15) & ~(size_t)15; return p; };
    bf16*  m_cur = (bf16*)alloc((size_t)E * 256 * 2);   // 102.4 MB
    bf16*  headF = (bf16*)alloc((size_t)E * 256 * 2);   // 102.4 MB
    bf16*  S1    = (bf16*)alloc((size_t)E * 256 * 2);   // 102.4 MB (scratch / Wxc chunks)
    float* agg   = (float*)alloc((size_t)E * 64 * 4);   // 51.2 MB (later xa bf16 [E,128])
    bf16*  xbuf  = (bf16*)alloc((size_t)E * 64 * 2);    // 25.6 MB (later Fe f32 [E])
    float* h_cur = (float*)alloc((size_t)N * 128 * 4);
    float* headE = (float*)alloc((size_t)N * 128 * 4);
    float* ha    = (float*)alloc((size_t)N * 128 * 4);  // later xE
    float* tA    = (float*)alloc((size_t)N * 128 * 4);
    float* Wt    = (float*)alloc((size_t)65536 * 4);
    if (off > ws_size) {
        fprintf(stderr, "kernel_launch: ws too small: need %zu have %zu\n", off, ws_size);
        return;
    }
    bf16*  xa = (bf16*)agg;    // [E,128] bf16, triplet agg region reused
    float* Fe = (float*)xbuf;  // [E] f32, xbuf region reused post-loop
    float* xE = ha;            // [N,128] f32 post-loop

    const float* nfp = nullptr;
    const bf16*  nbp = nullptr;
    const int*   nip = nullptr;

    // h0, m0, head slice-0 accumulators
    embed_h<<<(N * 128 + 255) / 256, 256, 0, stream>>>(z, atom_tab, h_cur, N);
    GEMM(AM_GATHER, EP_SILU, h_cur, rbf, idx_s, idx_t, W_edge_in, 256, m_cur, nbp, E, 256, 384);
    GEMM(AM_NORMAL, EP_PLAIN, m_cur, nbp, nip, nip, W_outF_in, 256, headF, nbp, E, 256, 256);
    GEMM(AM_NORMAL, EP_PLAIN, h_cur, nfp, nip, nip, W_outE_in, 128, headE, nfp, N, 128, 128);

    for (int b = 0; b < NB; ++b) {
        const float* Wr3 = rbf_w3 + (size_t)b * 128 * 256;
        const float* Wdn = W_down + (size_t)b * 256 * 64;
        const float* Wcb = W_cbf + (size_t)b * 7 * 16;
        const float* Wbl = W_bil + (size_t)b * 16 * 64 * 64;
        const float* Wup = W_up + (size_t)b * 64 * 256;
        const float* We0 = W_res_e + ((size_t)b * 4 + 0) * 256 * 256;
        const float* We1 = W_res_e + ((size_t)b * 4 + 1) * 256 * 256;
        const float* We2 = W_res_e + ((size_t)b * 4 + 2) * 256 * 256;
        const float* We3 = W_res_e + ((size_t)b * 4 + 3) * 256 * 256;
        const float* Wrh = rbf_wh + (size_t)b * 128 * 256;
        const float* Wea = W_e2a + (size_t)b * 256 * 128;
        const float* Wa0 = W_res_a + ((size_t)b * 2 + 0) * 128 * 128;
        const float* Wa1 = W_res_a + ((size_t)b * 2 + 1) * 128 * 128;

        // --- triplet path (uses ORIGINAL m; S1 is scratch throughout) ---
        GEMM(AM_NORMAL, EP_PLAIN, rbf, nfp, nip, nip, Wr3, 256, S1, nbp, E, 256, 128);
        GEMM(AM_MUL2, EP_PLAIN, m_cur, S1, nip, nip, Wdn, 64, xbuf, nbp, E, 64, 256);
        transpose_wbil<<<256, 256, 0, stream>>>(Wbl, Wt);
        hipMemsetAsync(agg, 0, (size_t)E * 64 * sizeof(float), stream);
        for (int cc0 = 0; cc0 < 16; cc0 += 4) {
            GEMM(AM_NORMAL, EP_PLAIN, xbuf, nbp, nip, nip, Wt + cc0 * 64, 1024, S1, nbp, E, 256, 64);
            triplet_combine<<<(T * 64 + 255) / 256, 256, 0, stream>>>(
                S1, cbf, Wcb, id3_ba, id3_ca, agg, T, cc0);
        }

        // --- residual part 1: m <- res1(m) ---
        GEMM(AM_NORMAL, EP_SILU, m_cur, nbp, nip, nip, We0, 256, S1, nbp, E, 256, 256);
        GEMM(AM_NORMAL, EP_RES2, S1, nbp, nip, nip, We1, 256, m_cur, nbp, E, 256, 256);
        // --- inject x3: m <- (m + silu(agg@Wup)) * INV2 ---
        GEMM(AM_NORMAL, EP_RES2, agg, nfp, nip, nip, Wup, 256, m_cur, nbp, E, 256, 64);
        // --- residual part 2 ---
        GEMM(AM_NORMAL, EP_SILU, m_cur, nbp, nip, nip, We2, 256, S1, nbp, E, 256, 256);
        GEMM(AM_NORMAL, EP_RES2, S1, nbp, nip, nip, We3, 256, m_cur, nbp, E, 256, 256);
        // --- F-head accumulator ---
        GEMM(AM_NORMAL, EP_ACCUM, m_cur, nbp, nip, nip,
             W_outF_in + (size_t)(b + 1) * 256 * 256, 256, headF, nbp, E, 256, 256);

        // --- atom update ---
        GEMM(AM_NORMAL, EP_PLAIN, rbf, nfp, nip, nip, Wrh, 256, S1, nbp, E, 256, 128);
        GEMM(AM_MUL2, EP_PLAIN, m_cur, S1, nip, nip, Wea, 128, xa, nbp, E, 128, 256);
        hipMemsetAsync(ha, 0, (size_t)N * 128 * sizeof(float), stream);
        scatter_ha<<<(E * 128 + 255) / 256, 256, 0, stream>>>(xa, idx_t, ha, E);
        GEMM(AM_NORMAL, EP_SILU, ha, nfp, nip, nip, Wa0, 128, tA, nfp, N, 128, 128);
        GEMM(AM_NORMAL, EP_RESADD, tA, nfp, nip, nip, Wa1, 128, h_cur, ha, N, 128, 128);
        GEMM(AM_NORMAL, EP_ACCUM, h_cur, nfp, nip, nip,
             W_outE_in + (size_t)(b + 1) * 128 * 128, 128, headE, nfp, N, 128, 128);
    }

    // --- F head: xF -> m_cur (dead), Fe -> xbuf region ---
    GEMM(AM_SILU, EP_SILU, headF, nbp, nip, nip, W_outF_res, 256, S1, nbp, E, 256, 256);
    GEMM(AM_NORMAL, EP_HEADRES, S1, nbp, nip, nip, W_outF_res + 256 * 256, 256, m_cur, headF, E, 256, 256);
    rowdot<<<(E * 64 + 255) / 256, 256, 0, stream>>>(m_cur, W_outF_fin, Fe, E, 256, 1);

    // --- E head + output ---
    hipMemsetAsync(out, 0, (size_t)out_size * sizeof(float), stream);
    GEMM(AM_SILU, EP_SILU, headE, nfp, nip, nip, W_outE_res, 128, tA, nfp, N, 128, 128);
    GEMM(AM_NORMAL, EP_HEADRES, tA, nfp, nip, nip, W_outE_res + 128 * 128, 128, xE, headE, N, 128, 128);
    rowdot<<<(N * 64 + 255) / 256, 256, 0, stream>>>(xE, W_outE_fin, out, N, 128, 4);
    scatter_forces<<<(E + 255) / 256, 256, 0, stream>>>(Fe, V_st, idx_t, out, E);
}

// Round 3
// 3804.644 us; speedup vs baseline: 2.1958x; 2.1958x over previous
//
#include <hip/hip_runtime.h>
#include <hip/hip_bf16.h>
#include <cstdio>

#define INV2 0.70710678118654752440f
typedef __hip_bfloat16 bf16;
typedef __attribute__((ext_vector_type(8))) short short8v;
typedef __attribute__((ext_vector_type(8))) unsigned short u16x8;
typedef __attribute__((ext_vector_type(4))) float f32x4;

__device__ __forceinline__ float silu_f(float v) { return v / (1.0f + __expf(-v)); }
__device__ __forceinline__ float bf2f(unsigned short u) {
    union { unsigned int i; float f; } t; t.i = ((unsigned int)u) << 16; return t.f;
}
__device__ __forceinline__ unsigned short f2bf(float x) {
    bf16 b = __float2bfloat16(x);
    return *reinterpret_cast<unsigned short*>(&b);
}
__device__ __forceinline__ float toF(float v) { return v; }
__device__ __forceinline__ float toF(bf16 v) { return __bfloat162float(v); }
__device__ __forceinline__ void stF(float* p, float v) { *p = v; }
__device__ __forceinline__ void stF(bf16* p, float v) { *p = __float2bfloat16(v); }

__device__ __forceinline__ void ld8f(const float* p, float* o) {
    const float4 a = ((const float4*)p)[0], b = ((const float4*)p)[1];
    o[0]=a.x; o[1]=a.y; o[2]=a.z; o[3]=a.w; o[4]=b.x; o[5]=b.y; o[6]=b.z; o[7]=b.w;
}
__device__ __forceinline__ void ld8f(const bf16* p, float* o) {
    const u16x8 u = *(const u16x8*)p;
#pragma unroll
    for (int j = 0; j < 8; j++) o[j] = bf2f(u[j]);
}

enum { AM_NORMAL = 0, AM_MUL2 = 1, AM_GATHER = 2, AM_SILU = 3 };
enum { EP_PLAIN = 0, EP_SILU = 1, EP_ACCUM = 2, EP_RES2 = 3, EP_RESADD = 4, EP_HEADRES = 5 };

// C[M,N] = epilogue( amode(A)[M,K] @ bf16(B)[K,N] ) via mfma_f32_16x16x32_bf16
// Tile: BM=128 x BN, BK=32, 256 threads (4 waves).
// LDS rows padded to 40 ushorts (80B) -> only 2-way bank aliasing on b128 frag reads.
template <int AMODE, int EPI, int BN, typename AT, typename CT>
__global__ __launch_bounds__(256) void mgemm(
    const AT* __restrict__ A, const AT* __restrict__ A2,
    const int* __restrict__ gs, const int* __restrict__ gt,
    const float* __restrict__ B, int ldb,
    CT* __restrict__ C, const CT* __restrict__ X,
    int Mrows, int Ncols, int K)
{
    constexpr int FM = (BN == 128) ? 4 : 2;   // 16-row frags per wave
    __shared__ __align__(16) unsigned short Als[128 * 40];
    __shared__ __align__(16) unsigned short Bls[BN * 40];
    const int tid = threadIdx.x;
    const int row0 = blockIdx.x * 128, col0 = blockIdx.y * BN;

    // A staging: thread -> (row sr, k-half sh)
    const int sr = tid >> 1;
    const int sh = (tid & 1) * 16;
    const int gr = row0 + sr;
    const bool rok = (gr < Mrows);
    int is_ = 0, it_ = 0;
    if (AMODE == AM_GATHER) { if (rok) { is_ = gs[gr]; it_ = gt[gr]; } }

    // B staging: thread -> (col bcol, k range kbase..kbase+KC-1)
    const int bcol = tid & (BN - 1);
    constexpr int KC = BN / 8;               // 8 (BN=64) or 16 (BN=128)
    const int kbase = (tid / BN) * KC;

    // MFMA ids
    const int l = tid & 63, wid = tid >> 6;
    const int lr = l & 15;                   // row-in-frag (A) / col-in-frag (B^T)
    const int lk = (l >> 4) * 8;             // k offset
    const int wrow = (BN == 128) ? ((wid & 1) * 64) : (wid * 32);
    const int wcol = (BN == 128) ? ((wid >> 1) * 64) : 0;

    f32x4 acc[FM][4];
#pragma unroll
    for (int i = 0; i < FM; i++)
#pragma unroll
        for (int j = 0; j < 4; j++)
#pragma unroll
            for (int q = 0; q < 4; q++) acc[i][j][q] = 0.f;

    for (int k0 = 0; k0 < K; k0 += 32) {
        // ---- stage A tile [128][32] (bf16, padded rows) ----
        float va[16];
        if (rok) {
            if (AMODE == AM_GATHER) {        // K==384: 128-wide regions h[is]|h[it]|rbf
                const int reg = k0 >> 7, koff = (k0 & 127) + sh;
                const AT* src = (reg == 0) ? (A + (size_t)is_ * 128 + koff)
                              : (reg == 1) ? (A + (size_t)it_ * 128 + koff)
                                           : (A2 + (size_t)gr * 128 + koff);
                ld8f(src, va); ld8f(src + 8, va + 8);
            } else {
                const AT* src = A + (size_t)gr * K + k0 + sh;
                ld8f(src, va); ld8f(src + 8, va + 8);
                if (AMODE == AM_MUL2) {
                    float vb[16];
                    const AT* s2 = A2 + (size_t)gr * K + k0 + sh;
                    ld8f(s2, vb); ld8f(s2 + 8, vb + 8);
#pragma unroll
                    for (int j = 0; j < 16; j++) va[j] *= vb[j];
                } else if (AMODE == AM_SILU) {
#pragma unroll
                    for (int j = 0; j < 16; j++) va[j] = silu_f(va[j]);
                }
            }
        } else {
#pragma unroll
            for (int j = 0; j < 16; j++) va[j] = 0.f;
        }
        u16x8 av0, av1;
#pragma unroll
        for (int j = 0; j < 8; j++) { av0[j] = f2bf(va[j]); av1[j] = f2bf(va[j + 8]); }
        *(u16x8*)&Als[sr * 40 + sh] = av0;
        *(u16x8*)&Als[sr * 40 + sh + 8] = av1;

        // ---- stage B^T tile [BN][32] (f32 -> bf16, transpose in flight) ----
        unsigned short bv[KC];
#pragma unroll
        for (int j = 0; j < KC; j++)
            bv[j] = f2bf(B[(size_t)(k0 + kbase + j) * ldb + col0 + bcol]);
        unsigned int* bd = (unsigned int*)Bls;
#pragma unroll
        for (int j = 0; j < KC / 2; j++)
            bd[bcol * 20 + (kbase >> 1) + j] =
                (unsigned int)bv[2 * j] | ((unsigned int)bv[2 * j + 1] << 16);

        __syncthreads();

        short8v af[FM], bfr[4];
#pragma unroll
        for (int fm = 0; fm < FM; fm++)
            af[fm] = *(const short8v*)&Als[(wrow + fm * 16 + lr) * 40 + lk];
#pragma unroll
        for (int fn = 0; fn < 4; fn++)
            bfr[fn] = *(const short8v*)&Bls[(wcol + fn * 16 + lr) * 40 + lk];
#pragma unroll
        for (int fm = 0; fm < FM; fm++)
#pragma unroll
            for (int fn = 0; fn < 4; fn++)
                acc[fm][fn] = __builtin_amdgcn_mfma_f32_16x16x32_bf16(
                    af[fm], bfr[fn], acc[fm][fn], 0, 0, 0);

        __syncthreads();
    }

    // ---- epilogue: C/D layout col=lane&15, row=(lane>>4)*4+reg ----
#pragma unroll
    for (int fm = 0; fm < FM; fm++) {
        const int rb = row0 + wrow + fm * 16 + (l >> 4) * 4;
#pragma unroll
        for (int fn = 0; fn < 4; fn++) {
            const int c = col0 + wcol + fn * 16 + lr;
#pragma unroll
            for (int r = 0; r < 4; r++) {
                const int rr = rb + r;
                if (rr >= Mrows) continue;
                const size_t o = (size_t)rr * Ncols + c;
                const float v = acc[fm][fn][r];
                if (EPI == EP_PLAIN)        stF(&C[o], v);
                else if (EPI == EP_SILU)    stF(&C[o], silu_f(v));
                else if (EPI == EP_ACCUM)   stF(&C[o], toF(C[o]) + v);
                else if (EPI == EP_RES2)    stF(&C[o], (toF(C[o]) + silu_f(v)) * INV2);
                else if (EPI == EP_RESADD)  stF(&C[o], toF(C[o]) + (toF(X[o]) + silu_f(v)) * INV2);
                else if (EPI == EP_HEADRES) stF(&C[o], (silu_f(toF(X[o])) + silu_f(v)) * INV2);
            }
        }
    }
}

__global__ __launch_bounds__(256) void embed_h(const int* __restrict__ z,
                                               const float* __restrict__ tab,
                                               float* __restrict__ h, int N)
{
    const int gid = blockIdx.x * 256 + threadIdx.x;
    const int n = gid >> 7, j = gid & 127;
    if (n >= N) return;
    h[(size_t)n * 128 + j] = tab[(size_t)z[n] * 128 + j];
}

// Wt[i, c*64+o] = Wb[c, i, o]   (Wb: [16,64,64])
__global__ __launch_bounds__(256) void transpose_wbil(const float* __restrict__ Wb,
                                                      float* __restrict__ Wt)
{
    const int idx = blockIdx.x * 256 + threadIdx.x;  // 65536
    const int o = idx & 63, i = (idx >> 6) & 63, c = idx >> 12;
    Wt[(size_t)i * 1024 + c * 64 + o] = Wb[idx];
}

// agg[ca[t],o] += sum_{cc<4} (cbf[t,:7].Wcb[:,cc0+cc]) * Wxc[ba[t], cc*64+o]
__global__ __launch_bounds__(256) void triplet_combine(
    const bf16* __restrict__ Wxc,   // [E,256]
    const float* __restrict__ cbf,  // [T,7]
    const float* __restrict__ Wcb,  // [7,16] (this block's)
    const int* __restrict__ ba, const int* __restrict__ ca,
    float* __restrict__ agg, int T, int cc0)
{
    const int gid = blockIdx.x * 256 + threadIdx.x;
    const int t = gid >> 6, o = gid & 63;
    if (t >= T) return;
    const int e = ba[t], eo = ca[t];
    const float* cr = cbf + (size_t)t * 7;
    float c0 = cr[0], c1 = cr[1], c2 = cr[2], c3 = cr[3], c4 = cr[4], c5 = cr[5], c6 = cr[6];
    const bf16* w = Wxc + (size_t)e * 256 + o;
    float y = 0.f;
#pragma unroll
    for (int cc = 0; cc < 4; cc++) {
        const float* wc = Wcb + cc0 + cc;
        const float cb = c0 * wc[0] + c1 * wc[16] + c2 * wc[32] + c3 * wc[48] +
                         c4 * wc[64] + c5 * wc[80] + c6 * wc[96];
        y += cb * toF(w[cc * 64]);
    }
    atomicAdd(&agg[(size_t)eo * 64 + o], y);
}

__global__ __launch_bounds__(256) void scatter_ha(const bf16* __restrict__ xa,
                                                  const int* __restrict__ idxt,
                                                  float* __restrict__ ha, int E)
{
    const int gid = blockIdx.x * 256 + threadIdx.x;
    const int e = gid >> 7, j = gid & 127;
    if (e >= E) return;
    atomicAdd(&ha[(size_t)idxt[e] * 128 + j], toF(xa[(size_t)e * 128 + j]));
}

// one wave per row: out[row*ostride] = X[row,:width] . w
template <typename AT>
__global__ __launch_bounds__(256) void rowdot(const AT* __restrict__ Xm,
                                              const float* __restrict__ w,
                                              float* __restrict__ outv,
                                              int rows, int width, int ostride)
{
    const int wid = (blockIdx.x * 256 + threadIdx.x) >> 6;
    const int lane = threadIdx.x & 63;
    if (wid >= rows) return;
    float s = 0.f;
    for (int q = lane; q < width; q += 64) s += toF(Xm[(size_t)wid * width + q]) * w[q];
#pragma unroll
    for (int off = 32; off > 0; off >>= 1) s += __shfl_down(s, off);
    if (lane == 0) outv[(size_t)wid * ostride] = s;
}

__global__ __launch_bounds__(256) void scatter_forces(const float* __restrict__ Fe,
                                                      const float* __restrict__ Vst,
                                                      const int* __restrict__ idxt,
                                                      float* __restrict__ out, int E)
{
    const int e = blockIdx.x * 256 + threadIdx.x;
    if (e >= E) return;
    const float f = Fe[e];
    const int n = idxt[e];
    atomicAdd(&out[(size_t)n * 4 + 1], f * Vst[(size_t)e * 3 + 0]);
    atomicAdd(&out[(size_t)n * 4 + 2], f * Vst[(size_t)e * 3 + 1]);
    atomicAdd(&out[(size_t)n * 4 + 3], f * Vst[(size_t)e * 3 + 2]);
}

#define MG(AM, EP, BNv, Aptr, A2p, GS, GT, Bp, LDB, Cp, Xp, MR, NC, KK)                  \
    mgemm<AM, EP, BNv><<<dim3(((MR) + 127) / 128, (NC) / (BNv)), 256, 0, stream>>>(      \
        Aptr, A2p, GS, GT, Bp, LDB, Cp, Xp, MR, NC, KK)

extern "C" void kernel_launch(void* const* d_in, const int* in_sizes, int n_in,
                              void* d_out, int out_size, void* d_ws, size_t ws_size,
                              hipStream_t stream)
{
    const int N = in_sizes[0];
    const int E = in_sizes[1];
    const int T = in_sizes[3];
    const int NB = 2;

    const int*   z        = (const int*)d_in[0];
    const int*   idx_s    = (const int*)d_in[1];
    const int*   idx_t    = (const int*)d_in[2];
    const int*   id3_ba   = (const int*)d_in[3];
    const int*   id3_ca   = (const int*)d_in[4];
    const float* rbf      = (const float*)d_in[5];
    const float* cbf      = (const float*)d_in[6];
    const float* V_st     = (const float*)d_in[7];
    const float* atom_tab = (const float*)d_in[8];
    const float* W_edge_in= (const float*)d_in[9];
    const float* rbf_w3   = (const float*)d_in[10];
    const float* W_down   = (const float*)d_in[11];
    const float* W_cbf    = (const float*)d_in[12];
    const float* W_bil    = (const float*)d_in[13];
    const float* W_up     = (const float*)d_in[14];
    const float* W_res_e  = (const float*)d_in[15];
    const float* rbf_wh   = (const float*)d_in[16];
    const float* W_e2a    = (const float*)d_in[17];
    const float* W_res_a  = (const float*)d_in[18];
    const float* W_outE_in  = (const float*)d_in[19];
    const float* W_outE_res = (const float*)d_in[20];
    const float* W_outE_fin = (const float*)d_in[21];
    const float* W_outF_in  = (const float*)d_in[22];
    const float* W_outF_res = (const float*)d_in[23];
    const float* W_outF_fin = (const float*)d_in[24];

    float* out = (float*)d_out;

    // ---- workspace layout (bytes) ----
    char* base = (char*)d_ws;
    size_t off = 0;
    auto alloc = [&](size_t nbytes) { char* p = base + off; off += (nbytes + 15) & ~(size_t)15; return p; };
    bf16*  m_cur = (bf16*)alloc((size_t)E * 256 * 2);
    bf16*  headF = (bf16*)alloc((size_t)E * 256 * 2);
    bf16*  S1    = (bf16*)alloc((size_t)E * 256 * 2);
    float* agg   = (float*)alloc((size_t)E * 64 * 4);
    bf16*  xbuf  = (bf16*)alloc((size_t)E * 64 * 2);
    float* h_cur = (float*)alloc((size_t)N * 128 * 4);
    float* headE = (float*)alloc((size_t)N * 128 * 4);
    float* ha    = (float*)alloc((size_t)N * 128 * 4);
    float* tA    = (float*)alloc((size_t)N * 128 * 4);
    float* Wt    = (float*)alloc((size_t)65536 * 4);
    if (off > ws_size) {
        fprintf(stderr, "kernel_launch: ws too small: need %zu have %zu\n", off, ws_size);
        return;
    }
    bf16*  xa = (bf16*)agg;    // [E,128] bf16, triplet agg region reused
    float* Fe = (float*)xbuf;  // [E] f32, xbuf region reused post-loop
    float* xE = ha;            // [N,128] f32 post-loop

    const float* nfp = nullptr;
    const bf16*  nbp = nullptr;
    const int*   nip = nullptr;

    // h0, m0, head slice-0 accumulators
    embed_h<<<(N * 128 + 255) / 256, 256, 0, stream>>>(z, atom_tab, h_cur, N);
    MG(AM_GATHER, EP_SILU, 128, h_cur, rbf, idx_s, idx_t, W_edge_in, 256, m_cur, nbp, E, 256, 384);
    MG(AM_NORMAL, EP_PLAIN, 128, m_cur, nbp, nip, nip, W_outF_in, 256, headF, nbp, E, 256, 256);
    MG(AM_NORMAL, EP_PLAIN, 64, h_cur, nfp, nip, nip, W_outE_in, 128, headE, nfp, N, 128, 128);

    for (int b = 0; b < NB; ++b) {
        const float* Wr3 = rbf_w3 + (size_t)b * 128 * 256;
        const float* Wdn = W_down + (size_t)b * 256 * 64;
        const float* Wcb = W_cbf + (size_t)b * 7 * 16;
        const float* Wbl = W_bil + (size_t)b * 16 * 64 * 64;
        const float* Wup = W_up + (size_t)b * 64 * 256;
        const float* We0 = W_res_e + ((size_t)b * 4 + 0) * 256 * 256;
        const float* We1 = W_res_e + ((size_t)b * 4 + 1) * 256 * 256;
        const float* We2 = W_res_e + ((size_t)b * 4 + 2) * 256 * 256;
        const float* We3 = W_res_e + ((size_t)b * 4 + 3) * 256 * 256;
        const float* Wrh = rbf_wh + (size_t)b * 128 * 256;
        const float* Wea = W_e2a + (size_t)b * 256 * 128;
        const float* Wa0 = W_res_a + ((size_t)b * 2 + 0) * 128 * 128;
        const float* Wa1 = W_res_a + ((size_t)b * 2 + 1) * 128 * 128;

        // --- triplet path ---
        MG(AM_NORMAL, EP_PLAIN, 128, rbf, nfp, nip, nip, Wr3, 256, S1, nbp, E, 256, 128);
        MG(AM_MUL2, EP_PLAIN, 64, m_cur, S1, nip, nip, Wdn, 64, xbuf, nbp, E, 64, 256);
        transpose_wbil<<<256, 256, 0, stream>>>(Wbl, Wt);
        hipMemsetAsync(agg, 0, (size_t)E * 64 * sizeof(float), stream);
        for (int cc0 = 0; cc0 < 16; cc0 += 4) {
            MG(AM_NORMAL, EP_PLAIN, 128, xbuf, nbp, nip, nip, Wt + cc0 * 64, 1024, S1, nbp, E, 256, 64);
            triplet_combine<<<(T * 64 + 255) / 256, 256, 0, stream>>>(
                S1, cbf, Wcb, id3_ba, id3_ca, agg, T, cc0);
        }

        // --- residual part 1: m <- res1(m) ---
        MG(AM_NORMAL, EP_SILU, 128, m_cur, nbp, nip, nip, We0, 256, S1, nbp, E, 256, 256);
        MG(AM_NORMAL, EP_RES2, 128, S1, nbp, nip, nip, We1, 256, m_cur, nbp, E, 256, 256);
        // --- inject x3: m <- (m + silu(agg@Wup)) * INV2 ---
        MG(AM_NORMAL, EP_RES2, 128, agg, nfp, nip, nip, Wup, 256, m_cur, nbp, E, 256, 64);
        // --- residual part 2 ---
        MG(AM_NORMAL, EP_SILU, 128, m_cur, nbp, nip, nip, We2, 256, S1, nbp, E, 256, 256);
        MG(AM_NORMAL, EP_RES2, 128, S1, nbp, nip, nip, We3, 256, m_cur, nbp, E, 256, 256);
        // --- F-head accumulator ---
        MG(AM_NORMAL, EP_ACCUM, 128, m_cur, nbp, nip, nip,
           W_outF_in + (size_t)(b + 1) * 256 * 256, 256, headF, nbp, E, 256, 256);

        // --- atom update ---
        MG(AM_NORMAL, EP_PLAIN, 128, rbf, nfp, nip, nip, Wrh, 256, S1, nbp, E, 256, 128);
        MG(AM_MUL2, EP_PLAIN, 128, m_cur, S1, nip, nip, Wea, 128, xa, nbp, E, 128, 256);
        hipMemsetAsync(ha, 0, (size_t)N * 128 * sizeof(float), stream);
        scatter_ha<<<(E * 128 + 255) / 256, 256, 0, stream>>>(xa, idx_t, ha, E);
        MG(AM_NORMAL, EP_SILU, 64, ha, nfp, nip, nip, Wa0, 128, tA, nfp, N, 128, 128);
        MG(AM_NORMAL, EP_RESADD, 64, tA, nfp, nip, nip, Wa1, 128, h_cur, ha, N, 128, 128);
        MG(AM_NORMAL, EP_ACCUM, 64, h_cur, nfp, nip, nip,
           W_outE_in + (size_t)(b + 1) * 128 * 128, 128, headE, nfp, N, 128, 128);
    }

    // --- F head ---
    MG(AM_SILU, EP_SILU, 128, headF, nbp, nip, nip, W_outF_res, 256, S1, nbp, E, 256, 256);
    MG(AM_NORMAL, EP_HEADRES, 128, S1, nbp, nip, nip, W_outF_res + 256 * 256, 256, m_cur, headF, E, 256, 256);
    rowdot<<<(E * 64 + 255) / 256, 256, 0, stream>>>(m_cur, W_outF_fin, Fe, E, 256, 1);

    // --- E head + output ---
    hipMemsetAsync(out, 0, (size_t)out_size * sizeof(float), stream);
    MG(AM_SILU, EP_SILU, 64, headE, nfp, nip, nip, W_outE_res, 128, tA, nfp, N, 128, 128);
    MG(AM_NORMAL, EP_HEADRES, 64, tA, nfp, nip, nip, W_outE_res + 128 * 128, 128, xE, headE, N, 128, 128);
    rowdot<<<(N * 64 + 255) / 256, 256, 0, stream>>>(xE, W_outE_fin, out, N, 128, 4);
    scatter_forces<<<(E + 255) / 256, 256, 0, stream>>>(Fe, V_st, idx_t, out, E);
}

// Round 4
// 3600.679 us; speedup vs baseline: 2.3202x; 1.0566x over previous
//
#include <hip/hip_runtime.h>
#include <hip/hip_bf16.h>
#include <cstdio>

#define INV2 0.70710678118654752440f
typedef __hip_bfloat16 bf16;
typedef __attribute__((ext_vector_type(8))) short short8v;
typedef __attribute__((ext_vector_type(8))) unsigned short u16x8;
typedef __attribute__((ext_vector_type(4))) float f32x4;

__device__ __forceinline__ float silu_f(float v) { return v / (1.0f + __expf(-v)); }
__device__ __forceinline__ float bf2f(unsigned short u) {
    union { unsigned int i; float f; } t; t.i = ((unsigned int)u) << 16; return t.f;
}
__device__ __forceinline__ unsigned short f2bf(float x) {
    bf16 b = __float2bfloat16(x);
    return *reinterpret_cast<unsigned short*>(&b);
}
__device__ __forceinline__ float toF(float v) { return v; }
__device__ __forceinline__ float toF(bf16 v) { return __bfloat162float(v); }
__device__ __forceinline__ void stF(float* p, float v) { *p = v; }
__device__ __forceinline__ void stF(bf16* p, float v) { *p = __float2bfloat16(v); }

__device__ __forceinline__ void ld8f(const float* p, float* o) {
    const float4 a = ((const float4*)p)[0], b = ((const float4*)p)[1];
    o[0]=a.x; o[1]=a.y; o[2]=a.z; o[3]=a.w; o[4]=b.x; o[5]=b.y; o[6]=b.z; o[7]=b.w;
}
__device__ __forceinline__ void ld8f(const bf16* p, float* o) {
    const u16x8 u = *(const u16x8*)p;
#pragma unroll
    for (int j = 0; j < 8; j++) o[j] = bf2f(u[j]);
}

// async global->LDS, 16B per lane; LDS dest = wave-uniform base + lane*16
__device__ __forceinline__ void gll16(const void* g, void* l) {
    __builtin_amdgcn_global_load_lds(
        (const __attribute__((address_space(1))) unsigned int*)g,
        (__attribute__((address_space(3))) unsigned int*)l, 16, 0, 0);
}

enum { AM_NORMAL = 0, AM_MUL2 = 1, AM_GATHER = 2, AM_SILU = 3, AM_DMA = 4 };
enum { EP_PLAIN = 0, EP_SILU = 1, EP_ACCUM = 2, EP_RES2 = 3, EP_RESADD = 4, EP_HEADRES = 5 };

// C[M,N] = epilogue( amode(A)[M,K] @ Bt^T )  with Bt = bf16 [Ncols][K] row-major.
// Tile BM=128 x BN, BK=32, 256 threads (4 waves), mfma_f32_16x16x32_bf16.
// AM_DMA: A bf16 row-major, staged via global_load_lds (linear LDS, stride 32).
// Other modes: A staged via registers into padded LDS (stride 40).
template <int AMODE, int EPI, int BN, typename AT, typename CT>
__global__ __launch_bounds__(256) void mgemm(
    const AT* __restrict__ A, const AT* __restrict__ A2,
    const int* __restrict__ gs, const int* __restrict__ gt,
    const bf16* __restrict__ Bt,
    CT* __restrict__ C, const CT* __restrict__ X,
    int Mrows, int Ncols, int K)
{
    constexpr bool DMA = (AMODE == AM_DMA);
    constexpr int AST = DMA ? 32 : 40;        // Als row stride (ushorts)
    constexpr int FM = (BN == 128) ? 4 : 2;
    __shared__ __align__(16) unsigned short Als[128 * AST];
    __shared__ __align__(16) unsigned short Bls[BN * 32];
    const int tid = threadIdx.x;
    const int row0 = blockIdx.x * 128, col0 = blockIdx.y * BN;

    // register-path A staging ids
    const int sr = tid >> 1;
    const int sh = (tid & 1) * 16;
    const int gr = row0 + sr;
    const bool rok = (gr < Mrows);
    int is_ = 0, it_ = 0;
    if (AMODE == AM_GATHER) { if (rok) { is_ = gs[gr]; it_ = gt[gr]; } }

    // MFMA ids
    const int l = tid & 63, wid = tid >> 6;
    const int lr = l & 15;
    const int lk = (l >> 4) * 8;
    const int wrow = (BN == 128) ? ((wid & 1) * 64) : (wid * 32);
    const int wcol = (BN == 128) ? ((wid >> 1) * 64) : 0;

    f32x4 acc[FM][4];
#pragma unroll
    for (int i = 0; i < FM; i++)
#pragma unroll
        for (int j = 0; j < 4; j++)
#pragma unroll
            for (int q = 0; q < 4; q++) acc[i][j][q] = 0.f;

    for (int k0 = 0; k0 < K; k0 += 32) {
        // ---- stage A tile [128][32] bf16 ----
        if constexpr (DMA) {
#pragma unroll
            for (int i = 0; i < 2; i++) {
                const int c = i * 256 + tid;
                const int row = c >> 2;
                if (row0 + row < Mrows)
                    gll16(A + (size_t)(row0 + row) * K + k0 + (c & 3) * 8, &Als[c * 8]);
            }
        } else {
            float va[16];
            if (rok) {
                if (AMODE == AM_GATHER) {    // K==384: regions h[is] | h[it] | rbf
                    const int reg = k0 >> 7, koff = (k0 & 127) + sh;
                    const AT* src = (reg == 0) ? (A + (size_t)is_ * 128 + koff)
                                  : (reg == 1) ? (A + (size_t)it_ * 128 + koff)
                                               : (A2 + (size_t)gr * 128 + koff);
                    ld8f(src, va); ld8f(src + 8, va + 8);
                } else {
                    const AT* src = A + (size_t)gr * K + k0 + sh;
                    ld8f(src, va); ld8f(src + 8, va + 8);
                    if (AMODE == AM_MUL2) {
                        float vb[16];
                        const AT* s2 = A2 + (size_t)gr * K + k0 + sh;
                        ld8f(s2, vb); ld8f(s2 + 8, vb + 8);
#pragma unroll
                        for (int j = 0; j < 16; j++) va[j] *= vb[j];
                    } else if (AMODE == AM_SILU) {
#pragma unroll
                        for (int j = 0; j < 16; j++) va[j] = silu_f(va[j]);
                    }
                }
            } else {
#pragma unroll
                for (int j = 0; j < 16; j++) va[j] = 0.f;
            }
            u16x8 av0, av1;
#pragma unroll
            for (int j = 0; j < 8; j++) { av0[j] = f2bf(va[j]); av1[j] = f2bf(va[j + 8]); }
            *(u16x8*)&Als[sr * AST + sh] = av0;
            *(u16x8*)&Als[sr * AST + sh + 8] = av1;
        }

        // ---- stage B^T tile [BN][32] via DMA (Bt bf16 [Ncols][K]) ----
#pragma unroll
        for (int i = 0; i < BN / 64; i++) {
            const int c = i * 256 + tid;
            gll16(Bt + (size_t)(col0 + (c >> 2)) * K + k0 + (c & 3) * 8, &Bls[c * 8]);
        }

        __syncthreads();

        short8v af[FM], bfr[4];
#pragma unroll
        for (int fm = 0; fm < FM; fm++)
            af[fm] = *(const short8v*)&Als[(wrow + fm * 16 + lr) * AST + lk];
#pragma unroll
        for (int fn = 0; fn < 4; fn++)
            bfr[fn] = *(const short8v*)&Bls[(wcol + fn * 16 + lr) * 32 + lk];
#pragma unroll
        for (int fm = 0; fm < FM; fm++)
#pragma unroll
            for (int fn = 0; fn < 4; fn++)
                acc[fm][fn] = __builtin_amdgcn_mfma_f32_16x16x32_bf16(
                    af[fm], bfr[fn], acc[fm][fn], 0, 0, 0);

        __syncthreads();
    }

    // ---- epilogue: C/D layout col=lane&15, row=(lane>>4)*4+reg ----
#pragma unroll
    for (int fm = 0; fm < FM; fm++) {
        const int rb = row0 + wrow + fm * 16 + (l >> 4) * 4;
#pragma unroll
        for (int fn = 0; fn < 4; fn++) {
            const int c = col0 + wcol + fn * 16 + lr;
#pragma unroll
            for (int r = 0; r < 4; r++) {
                const int rr = rb + r;
                if (rr >= Mrows) continue;
                const size_t o = (size_t)rr * Ncols + c;
                const float v = acc[fm][fn][r];
                if (EPI == EP_PLAIN)        stF(&C[o], v);
                else if (EPI == EP_SILU)    stF(&C[o], silu_f(v));
                else if (EPI == EP_ACCUM)   stF(&C[o], toF(C[o]) + v);
                else if (EPI == EP_RES2)    stF(&C[o], (toF(C[o]) + silu_f(v)) * INV2);
                else if (EPI == EP_RESADD)  stF(&C[o], toF(C[o]) + (toF(X[o]) + silu_f(v)) * INV2);
                else if (EPI == EP_HEADRES) stF(&C[o], (silu_f(toF(X[o])) + silu_f(v)) * INV2);
            }
        }
    }
}

// ---- weight pre-transpose: dst[n*K+k] = bf16(src[k*N+n]) ----
struct TJob { const float* src; bf16* dst; int K; int N; };
struct TJobs { TJob j[65]; };

__global__ __launch_bounds__(256) void transpose_weights(TJobs JB) {
    const TJob J = JB.j[blockIdx.y];
    const int total = J.K * J.N;
    const int gid = blockIdx.x * 256 + threadIdx.x;
    if (gid >= total) return;
    const int n = gid / J.K, k = gid - n * J.K;
    J.dst[(size_t)n * J.K + k] = __float2bfloat16(J.src[(size_t)k * J.N + n]);
}

__global__ __launch_bounds__(256) void embed_h(const int* __restrict__ z,
                                               const float* __restrict__ tab,
                                               float* __restrict__ h, int N)
{
    const int gid = blockIdx.x * 256 + threadIdx.x;
    const int n = gid >> 7, j = gid & 127;
    if (n >= N) return;
    h[(size_t)n * 128 + j] = tab[(size_t)z[n] * 128 + j];
}

// agg[ca[t],o] += sum_{cc<4} (cbf[t,:7].Wcb[:,cc0+cc]) * Wxc[ba[t], cc*64+o]
__global__ __launch_bounds__(256) void triplet_combine(
    const bf16* __restrict__ Wxc,   // [E,256]
    const float* __restrict__ cbf,  // [T,7]
    const float* __restrict__ Wcb,  // [7,16] (this block's)
    const int* __restrict__ ba, const int* __restrict__ ca,
    float* __restrict__ agg, int T, int cc0)
{
    const int gid = blockIdx.x * 256 + threadIdx.x;
    const int t = gid >> 6, o = gid & 63;
    if (t >= T) return;
    const int e = ba[t], eo = ca[t];
    const float* cr = cbf + (size_t)t * 7;
    float c0 = cr[0], c1 = cr[1], c2 = cr[2], c3 = cr[3], c4 = cr[4], c5 = cr[5], c6 = cr[6];
    const bf16* w = Wxc + (size_t)e * 256 + o;
    float y = 0.f;
#pragma unroll
    for (int cc = 0; cc < 4; cc++) {
        const float* wc = Wcb + cc0 + cc;
        const float cb = c0 * wc[0] + c1 * wc[16] + c2 * wc[32] + c3 * wc[48] +
                         c4 * wc[64] + c5 * wc[80] + c6 * wc[96];
        y += cb * toF(w[cc * 64]);
    }
    atomicAdd(&agg[(size_t)eo * 64 + o], y);
}

__global__ __launch_bounds__(256) void scatter_ha(const bf16* __restrict__ xa,
                                                  const int* __restrict__ idxt,
                                                  float* __restrict__ ha, int E)
{
    const int gid = blockIdx.x * 256 + threadIdx.x;
    const int e = gid >> 7, j = gid & 127;
    if (e >= E) return;
    atomicAdd(&ha[(size_t)idxt[e] * 128 + j], toF(xa[(size_t)e * 128 + j]));
}

// one wave per row: out[row*ostride] = X[row,:width] . w
template <typename AT>
__global__ __launch_bounds__(256) void rowdot(const AT* __restrict__ Xm,
                                              const float* __restrict__ w,
                                              float* __restrict__ outv,
                                              int rows, int width, int ostride)
{
    const int wid = (blockIdx.x * 256 + threadIdx.x) >> 6;
    const int lane = threadIdx.x & 63;
    if (wid >= rows) return;
    float s = 0.f;
    for (int q = lane; q < width; q += 64) s += toF(Xm[(size_t)wid * width + q]) * w[q];
#pragma unroll
    for (int off = 32; off > 0; off >>= 1) s += __shfl_down(s, off);
    if (lane == 0) outv[(size_t)wid * ostride] = s;
}

__global__ __launch_bounds__(256) void scatter_forces(const float* __restrict__ Fe,
                                                      const float* __restrict__ Vst,
                                                      const int* __restrict__ idxt,
                                                      float* __restrict__ out, int E)
{
    const int e = blockIdx.x * 256 + threadIdx.x;
    if (e >= E) return;
    const float f = Fe[e];
    const int n = idxt[e];
    atomicAdd(&out[(size_t)n * 4 + 1], f * Vst[(size_t)e * 3 + 0]);
    atomicAdd(&out[(size_t)n * 4 + 2], f * Vst[(size_t)e * 3 + 1]);
    atomicAdd(&out[(size_t)n * 4 + 3], f * Vst[(size_t)e * 3 + 2]);
}

#define MG(AM, EP, BNv, Aptr, A2p, GS, GT, Btp, Cp, Xp, MR, NC, KK)                       \
    mgemm<AM, EP, BNv><<<dim3(((MR) + 127) / 128, (NC) / (BNv)), 256, 0, stream>>>(       \
        Aptr, A2p, GS, GT, Btp, Cp, Xp, MR, NC, KK)

extern "C" void kernel_launch(void* const* d_in, const int* in_sizes, int n_in,
                              void* d_out, int out_size, void* d_ws, size_t ws_size,
                              hipStream_t stream)
{
    const int N = in_sizes[0];
    const int E = in_sizes[1];
    const int T = in_sizes[3];
    const int NB = 2;

    const int*   z        = (const int*)d_in[0];
    const int*   idx_s    = (const int*)d_in[1];
    const int*   idx_t    = (const int*)d_in[2];
    const int*   id3_ba   = (const int*)d_in[3];
    const int*   id3_ca   = (const int*)d_in[4];
    const float* rbf      = (const float*)d_in[5];
    const float* cbf      = (const float*)d_in[6];
    const float* V_st     = (const float*)d_in[7];
    const float* atom_tab = (const float*)d_in[8];
    const float* W_edge_in= (const float*)d_in[9];
    const float* rbf_w3   = (const float*)d_in[10];
    const float* W_down   = (const float*)d_in[11];
    const float* W_cbf    = (const float*)d_in[12];
    const float* W_bil    = (const float*)d_in[13];
    const float* W_up     = (const float*)d_in[14];
    const float* W_res_e  = (const float*)d_in[15];
    const float* rbf_wh   = (const float*)d_in[16];
    const float* W_e2a    = (const float*)d_in[17];
    const float* W_res_a  = (const float*)d_in[18];
    const float* W_outE_in  = (const float*)d_in[19];
    const float* W_outE_res = (const float*)d_in[20];
    const float* W_outE_fin = (const float*)d_in[21];
    const float* W_outF_in  = (const float*)d_in[22];
    const float* W_outF_res = (const float*)d_in[23];
    const float* W_outF_fin = (const float*)d_in[24];

    float* out = (float*)d_out;

    // ---- workspace layout ----
    char* base = (char*)d_ws;
    size_t off = 0;
    auto alloc = [&](size_t nbytes) { char* p = base + off; off += (nbytes + 15) & ~(size_t)15; return p; };
    bf16*  m_cur = (bf16*)alloc((size_t)E * 256 * 2);
    bf16*  headF = (bf16*)alloc((size_t)E * 256 * 2);
    bf16*  S1    = (bf16*)alloc((size_t)E * 256 * 2);
    float* agg   = (float*)alloc((size_t)E * 64 * 4);
    bf16*  xbuf  = (bf16*)alloc((size_t)E * 64 * 2);
    float* h_cur = (float*)alloc((size_t)N * 128 * 4);
    float* headE = (float*)alloc((size_t)N * 128 * 4);
    float* ha    = (float*)alloc((size_t)N * 128 * 4);
    float* tA    = (float*)alloc((size_t)N * 128 * 4);
    // bf16 transposed weight pool (~3 MB)
    bf16 *bt_outF[3], *bt_outE[3], *bt_r3[2], *bt_down[2], *bt_bil[2], *bt_up[2],
         *bt_rese[8], *bt_rh[2], *bt_e2a[2], *bt_resa[4], *bt_Fres[2], *bt_Eres[2];
    bf16* bt_edge = (bf16*)alloc(384 * 256 * 2);
    for (int s = 0; s < 3; s++) bt_outF[s] = (bf16*)alloc(256 * 256 * 2);
    for (int s = 0; s < 3; s++) bt_outE[s] = (bf16*)alloc(128 * 128 * 2);
    for (int b = 0; b < 2; b++) bt_r3[b]   = (bf16*)alloc(256 * 128 * 2);
    for (int b = 0; b < 2; b++) bt_down[b] = (bf16*)alloc(64 * 256 * 2);
    for (int b = 0; b < 2; b++) bt_bil[b]  = (bf16*)alloc(1024 * 64 * 2);
    for (int b = 0; b < 2; b++) bt_up[b]   = (bf16*)alloc(256 * 64 * 2);
    for (int i = 0; i < 8; i++) bt_rese[i] = (bf16*)alloc(256 * 256 * 2);
    for (int b = 0; b < 2; b++) bt_rh[b]   = (bf16*)alloc(256 * 128 * 2);
    for (int b = 0; b < 2; b++) bt_e2a[b]  = (bf16*)alloc(128 * 256 * 2);
    for (int i = 0; i < 4; i++) bt_resa[i] = (bf16*)alloc(128 * 128 * 2);
    for (int i = 0; i < 2; i++) bt_Fres[i] = (bf16*)alloc(256 * 256 * 2);
    for (int i = 0; i < 2; i++) bt_Eres[i] = (bf16*)alloc(128 * 128 * 2);
    if (off > ws_size) {
        fprintf(stderr, "kernel_launch: ws too small: need %zu have %zu\n", off, ws_size);
        return;
    }
    bf16*  xa = (bf16*)agg;    // [E,128] bf16, agg region reused
    float* Fe = (float*)xbuf;  // [E] f32, xbuf region reused post-loop
    float* xE = ha;            // [N,128] f32 post-loop

    const float* nfp = nullptr;
    const bf16*  nbp = nullptr;
    const int*   nip = nullptr;

    // ---- weight transposes (one kernel, 65 jobs) ----
    {
        TJobs JB; int nj = 0;
        auto addj = [&](const float* s, bf16* d, int K, int Nn) { JB.j[nj++] = TJob{s, d, K, Nn}; };
        addj(W_edge_in, bt_edge, 384, 256);
        for (int s = 0; s < 3; s++) addj(W_outF_in + (size_t)s * 256 * 256, bt_outF[s], 256, 256);
        for (int s = 0; s < 3; s++) addj(W_outE_in + (size_t)s * 128 * 128, bt_outE[s], 128, 128);
        for (int b = 0; b < 2; b++) addj(rbf_w3 + (size_t)b * 128 * 256, bt_r3[b], 128, 256);
        for (int b = 0; b < 2; b++) addj(W_down + (size_t)b * 256 * 64, bt_down[b], 256, 64);
        for (int b = 0; b < 2; b++)
            for (int c = 0; c < 16; c++)
                addj(W_bil + ((size_t)b * 16 + c) * 4096, bt_bil[b] + c * 4096, 64, 64);
        for (int b = 0; b < 2; b++) addj(W_up + (size_t)b * 64 * 256, bt_up[b], 64, 256);
        for (int i = 0; i < 8; i++) addj(W_res_e + (size_t)i * 65536, bt_rese[i], 256, 256);
        for (int b = 0; b < 2; b++) addj(rbf_wh + (size_t)b * 128 * 256, bt_rh[b], 128, 256);
        for (int b = 0; b < 2; b++) addj(W_e2a + (size_t)b * 256 * 128, bt_e2a[b], 256, 128);
        for (int i = 0; i < 4; i++) addj(W_res_a + (size_t)i * 16384, bt_resa[i], 128, 128);
        for (int i = 0; i < 2; i++) addj(W_outF_res + (size_t)i * 65536, bt_Fres[i], 256, 256);
        for (int i = 0; i < 2; i++) addj(W_outE_res + (size_t)i * 16384, bt_Eres[i], 128, 128);
        transpose_weights<<<dim3(384, nj), 256, 0, stream>>>(JB);
    }

    // h0, m0, head slice-0 accumulators
    embed_h<<<(N * 128 + 255) / 256, 256, 0, stream>>>(z, atom_tab, h_cur, N);
    MG(AM_GATHER, EP_SILU, 128, h_cur, rbf, idx_s, idx_t, bt_edge, m_cur, nbp, E, 256, 384);
    MG(AM_DMA, EP_PLAIN, 128, m_cur, nbp, nip, nip, bt_outF[0], headF, nbp, E, 256, 256);
    MG(AM_NORMAL, EP_PLAIN, 64, h_cur, nfp, nip, nip, bt_outE[0], headE, nfp, N, 128, 128);

    for (int b = 0; b < NB; ++b) {
        const float* Wcb = W_cbf + (size_t)b * 7 * 16;

        // --- triplet path ---
        MG(AM_NORMAL, EP_PLAIN, 128, rbf, nfp, nip, nip, bt_r3[b], S1, nbp, E, 256, 128);
        MG(AM_MUL2, EP_PLAIN, 64, m_cur, S1, nip, nip, bt_down[b], xbuf, nbp, E, 64, 256);
        hipMemsetAsync(agg, 0, (size_t)E * 64 * sizeof(float), stream);
        for (int cc0 = 0; cc0 < 16; cc0 += 4) {
            MG(AM_DMA, EP_PLAIN, 128, xbuf, nbp, nip, nip, bt_bil[b] + cc0 * 4096, S1, nbp, E, 256, 64);
            triplet_combine<<<(T * 64 + 255) / 256, 256, 0, stream>>>(
                S1, cbf, Wcb, id3_ba, id3_ca, agg, T, cc0);
        }

        // --- residual part 1: m <- res1(m) ---
        MG(AM_DMA, EP_SILU, 128, m_cur, nbp, nip, nip, bt_rese[4 * b + 0], S1, nbp, E, 256, 256);
        MG(AM_DMA, EP_RES2, 128, S1, nbp, nip, nip, bt_rese[4 * b + 1], m_cur, nbp, E, 256, 256);
        // --- inject x3: m <- (m + silu(agg@Wup)) * INV2 ---
        MG(AM_NORMAL, EP_RES2, 128, agg, nfp, nip, nip, bt_up[b], m_cur, nbp, E, 256, 64);
        // --- residual part 2 ---
        MG(AM_DMA, EP_SILU, 128, m_cur, nbp, nip, nip, bt_rese[4 * b + 2], S1, nbp, E, 256, 256);
        MG(AM_DMA, EP_RES2, 128, S1, nbp, nip, nip, bt_rese[4 * b + 3], m_cur, nbp, E, 256, 256);
        // --- F-head accumulator ---
        MG(AM_DMA, EP_ACCUM, 128, m_cur, nbp, nip, nip, bt_outF[b + 1], headF, nbp, E, 256, 256);

        // --- atom update ---
        MG(AM_NORMAL, EP_PLAIN, 128, rbf, nfp, nip, nip, bt_rh[b], S1, nbp, E, 256, 128);
        MG(AM_MUL2, EP_PLAIN, 128, m_cur, S1, nip, nip, bt_e2a[b], xa, nbp, E, 128, 256);
        hipMemsetAsync(ha, 0, (size_t)N * 128 * sizeof(float), stream);
        scatter_ha<<<(E * 128 + 255) / 256, 256, 0, stream>>>(xa, idx_t, ha, E);
        MG(AM_NORMAL, EP_SILU, 64, ha, nfp, nip, nip, bt_resa[2 * b + 0], tA, nfp, N, 128, 128);
        MG(AM_NORMAL, EP_RESADD, 64, tA, nfp, nip, nip, bt_resa[2 * b + 1], h_cur, ha, N, 128, 128);
        MG(AM_NORMAL, EP_ACCUM, 64, h_cur, nfp, nip, nip, bt_outE[b + 1], headE, nfp, N, 128, 128);
    }

    // --- F head ---
    MG(AM_SILU, EP_SILU, 128, headF, nbp, nip, nip, bt_Fres[0], S1, nbp, E, 256, 256);
    MG(AM_DMA, EP_HEADRES, 128, S1, nbp, nip, nip, bt_Fres[1], m_cur, headF, E, 256, 256);
    rowdot<<<(E * 64 + 255) / 256, 256, 0, stream>>>(m_cur, W_outF_fin, Fe, E, 256, 1);

    // --- E head + output ---
    hipMemsetAsync(out, 0, (size_t)out_size * sizeof(float), stream);
    MG(AM_SILU, EP_SILU, 64, headE, nfp, nip, nip, bt_Eres[0], tA, nfp, N, 128, 128);
    MG(AM_NORMAL, EP_HEADRES, 64, tA, nfp, nip, nip, bt_Eres[1], xE, headE, N, 128, 128);
    rowdot<<<(N * 64 + 255) / 256, 256, 0, stream>>>(xE, W_outE_fin, out, N, 128, 4);
    scatter_forces<<<(E + 255) / 256, 256, 0, stream>>>(Fe, V_st, idx_t, out, E);
}